// Round 12
// baseline (247.821 us; speedup 1.0000x reference)
//
#include <hip/hip_runtime.h>

// Segmented CRF forward (OneCrfCCKSDecoder), exp-domain + fp8 MFMA, R12.
// T=128, B=512, E=128, EVENTLEN=8, NEG=-10000.
//
// R11 NaN post-mortem: fixed e^-6 pre-scale parked h at fp8-e4m3's subnormal
// floor (window [2^-9,448]); full flush -> cmax=0 -> rcp=inf -> NaN. R12
// keeps R11's structure (4 waves x 2 j-tiles, G=2 pipelined batch groups,
// fp8 H+E with 2 ds_read_b128/wave/group) and fixes ONLY numerics+races:
//  - scale = e^-1 / cmax_stale (one-step-stale exact renorm, M += log exact)
//    -> h centered ~e^[0..4], max <~e^5.5 < 448; tiny entries flushing to 0
//    contribute <e^-12 of the logsumexp (harmless).
//  - h clamped to 440 pre-convert; cmax>=1e-30, r>=1e-35 guards.
//  - parity double-buffered Hbuf/Mpart/Spart: with the lgkm-drain barrier,
//    provably race-free (R9-R11 carried a latent read->next-write race).
// Slot mapping (validated family): A[m=bloc][k=32kap+8q+i],
// B[k=32kap+8q+i][n=bloc], D[m=4q+r][n=bloc]; H in-row addr qk*32+kap*8+i.
// E row 0 / te[127] exactly 0 (matches fp32 exp(-10000)=0).

typedef float f32x4 __attribute__((ext_vector_type(4)));
typedef long  lx2   __attribute__((ext_vector_type(2)));

#define NEG_VAL (-10000.0f)
#define S_SCALE 0.36787944117144233f   // e^-1
#define LOG_S   1.0f

// order own LDS ops + join wg; does NOT drain vmcnt (feat prefetch stays in
// flight across the barrier)
#define LDS_BARRIER() asm volatile("s_waitcnt lgkmcnt(0)\n\ts_barrier" ::: "memory")

__global__ __launch_bounds__(256, 1)
void crf_fwd(const float* __restrict__ feats,   // [128][512][128] f32
             const float* __restrict__ trans,   // [128][128] f32
             float* __restrict__ out)
{
    const int tid  = threadIdx.x;
    const int w    = tid >> 6;        // wave 0..3: owns j-tiles 2w,2w+1; writer kap=w
    const int lane = tid & 63;
    const int bloc = lane & 15;       // batch-in-tile (n); row index for A (m)
    const int q    = lane >> 4;       // quad

    // ---- A fragments: fp8(exp(T)) for tiles 2w,2w+1, kap 0..3 ----
    long Af[2][4];
    #pragma unroll
    for (int tile = 0; tile < 2; ++tile) {
        const float* rowp = trans + (size_t)(16 * (2 * w + tile) + bloc) * 128;
        #pragma unroll
        for (int kap = 0; kap < 4; ++kap) {
            const float* p = rowp + 32 * kap + 8 * q;
            float e0=__expf(p[0]), e1=__expf(p[1]), e2=__expf(p[2]), e3=__expf(p[3]);
            float e4=__expf(p[4]), e5=__expf(p[5]), e6=__expf(p[6]), e7=__expf(p[7]);
            int lo = __builtin_amdgcn_cvt_pk_fp8_f32(e0, e1, 0, false);
            lo     = __builtin_amdgcn_cvt_pk_fp8_f32(e2, e3, lo, true);
            int hi = __builtin_amdgcn_cvt_pk_fp8_f32(e4, e5, 0, false);
            hi     = __builtin_amdgcn_cvt_pk_fp8_f32(e6, e7, hi, true);
            Af[tile][kap] = (long)(((unsigned long long)(unsigned)hi << 32) | (unsigned)lo);
        }
    }
    // te in D layout: te[tile][r] = exp(trans[127][16*(2w+tile)+4q+r])
    f32x4 te[2];
    #pragma unroll
    for (int tile = 0; tile < 2; ++tile) {
        const float* p = trans + 127 * 128 + 16 * (2 * w + tile) + 4 * q;
        te[tile][0] = __expf(p[0]); te[tile][1] = __expf(p[1]);
        te[tile][2] = __expf(p[2]); te[tile][3] = __expf(p[3]);
    }

    // ---- LDS (parity double-buffered): H rows 144B-padded, partials ----
    __shared__ __align__(16) char  Hbuf[2][2][16 * 144];   // [parity][group]
    __shared__ __align__(16) float Mpart[2][2][64];        // [parity][group][bloc*4+w]
    __shared__ __align__(16) float Spart[2][2][64];

    // h write offsets within a row (4B each): k = 32w + 16*tile + 4q + r
    // -> qk=(2*tile+(q>>1)), kap=w, i0=4*(q&1)
    int woff[2];
    #pragma unroll
    for (int tile = 0; tile < 2; ++tile)
        woff[tile] = bloc * 144 + (2 * tile + (q >> 1)) * 32 + w * 8 + 4 * (q & 1);
    const int roff = bloc * 144 + q * 32;   // lane's contiguous 32B (kap-major)

    // ---- per-group state (G=2, batches blockIdx*32 + g*16 + bloc) ----
    const float* fb[2][2];
    float M[2], alpha[2], scp[2], lgp[2], lgb[2];
    f32x4 acc[2][2], efi[2][2], r1[2][2], r2[2][2];
    #pragma unroll
    for (int g = 0; g < 2; ++g) {
        const int b = blockIdx.x * 32 + g * 16 + bloc;
        #pragma unroll
        for (int tile = 0; tile < 2; ++tile) {
            const float* f = feats + (size_t)b * 128 + 32 * w + 16 * tile + 4 * q;
            fb[g][tile] = f;
            f32x4 x = *(const f32x4*)(f + 1 * 65536);
            f32x4 e;
            e[0] = __expf(x[0]) * S_SCALE; e[1] = __expf(x[1]) * S_SCALE;
            e[2] = __expf(x[2]) * S_SCALE; e[3] = __expf(x[3]) * S_SCALE;
            efi[g][tile] = e;
            r1[g][tile] = *(const f32x4*)(f + 2 * 65536);
            r2[g][tile] = *(const f32x4*)(f + 3 * 65536);
            acc[g][tile][0] = 1.f; acc[g][tile][1] = 1.f;
            acc[g][tile][2] = 1.f; acc[g][tile][3] = 1.f;
        }
        M[g]     = (b == 0) ? 0.0f : NEG_VAL;  // init_fv zeroes only batch-0 row
        alpha[g] = 0.0f;
        scp[g]   = S_SCALE;   // pending scale for next efi build
        lgp[g]   = LOG_S;
        lgb[g]   = LOG_S;     // log of inverse scale baked into current efi
    }

    for (int t = 1; t < 128; ++t) {
        const bool upd = (t & 7) != 0;
        const int  p   = t & 1;        // LDS parity
        #pragma unroll
        for (int g = 0; g < 2; ++g) {
            char*  Hb = Hbuf[p][g];
            float* Mp = Mpart[p][g];
            float* Sp = Spart[p][g];
            if (upd) {
                // ---- publish h = u(t-1)*efi (scale baked; M exact) ----
                M[g] += lgb[g];
                #pragma unroll
                for (int tile = 0; tile < 2; ++tile) {
                    f32x4 h = acc[g][tile] * efi[g][tile];
                    h[0] = fminf(h[0], 440.f); h[1] = fminf(h[1], 440.f);
                    h[2] = fminf(h[2], 440.f); h[3] = fminf(h[3], 440.f);
                    int v = __builtin_amdgcn_cvt_pk_fp8_f32(h[0], h[1], 0, false);
                    v     = __builtin_amdgcn_cvt_pk_fp8_f32(h[2], h[3], v, true);
                    *(int*)(Hb + woff[tile]) = v;
                }
                // one-step-stale renorm partial: wave-local max of u(t-1)
                float m = fmaxf(
                    fmaxf(fmaxf(acc[g][0][0], acc[g][0][1]), fmaxf(acc[g][0][2], acc[g][0][3])),
                    fmaxf(fmaxf(acc[g][1][0], acc[g][1][1]), fmaxf(acc[g][1][2], acc[g][1][3])));
                m = fmaxf(m, __shfl_xor(m, 16, 64));
                m = fmaxf(m, __shfl_xor(m, 32, 64));
                if (q == 0) Mp[bloc * 4 + w] = m;
                LDS_BARRIER();

                lx2 B01 = *(const lx2*)(Hb + roff);        // kap 0,1
                lx2 B23 = *(const lx2*)(Hb + roff + 16);   // kap 2,3
                f32x4 mp = *(const f32x4*)&Mp[bloc * 4];
                float cmax = fmaxf(fmaxf(fmaxf(mp[0], mp[1]), fmaxf(mp[2], mp[3])),
                                   1e-30f);

                // ---- 8 fp8 MFMAs, 4 independent chains of 2 ----
                f32x4 z = {0.f, 0.f, 0.f, 0.f};
                f32x4 dA = __builtin_amdgcn_mfma_f32_16x16x32_fp8_fp8(Af[0][0], B01[0], z, 0, 0, 0);
                f32x4 dB = __builtin_amdgcn_mfma_f32_16x16x32_fp8_fp8(Af[0][1], B01[1], z, 0, 0, 0);
                f32x4 dC = __builtin_amdgcn_mfma_f32_16x16x32_fp8_fp8(Af[1][0], B01[0], z, 0, 0, 0);
                f32x4 dD = __builtin_amdgcn_mfma_f32_16x16x32_fp8_fp8(Af[1][1], B01[1], z, 0, 0, 0);
                dA = __builtin_amdgcn_mfma_f32_16x16x32_fp8_fp8(Af[0][2], B23[0], dA, 0, 0, 0);
                dB = __builtin_amdgcn_mfma_f32_16x16x32_fp8_fp8(Af[0][3], B23[1], dB, 0, 0, 0);
                dC = __builtin_amdgcn_mfma_f32_16x16x32_fp8_fp8(Af[1][2], B23[0], dC, 0, 0, 0);
                dD = __builtin_amdgcn_mfma_f32_16x16x32_fp8_fp8(Af[1][3], B23[1], dD, 0, 0, 0);
                acc[g][0] = dA + dB;
                acc[g][1] = dC + dD;

                scp[g] = S_SCALE * __builtin_amdgcn_rcpf(cmax);
                lgp[g] = LOG_S + __logf(cmax);
            } else {
                // ---- event boundary: alpha += M + log(sum_j u*te) ----
                float s = acc[g][0][0]*te[0][0] + acc[g][0][1]*te[0][1]
                        + acc[g][0][2]*te[0][2] + acc[g][0][3]*te[0][3]
                        + acc[g][1][0]*te[1][0] + acc[g][1][1]*te[1][1]
                        + acc[g][1][2]*te[1][2] + acc[g][1][3]*te[1][3];
                s += __shfl_xor(s, 16, 64);
                s += __shfl_xor(s, 32, 64);
                if (q == 0) Sp[bloc * 4 + w] = s;
                LDS_BARRIER();
                f32x4 sp = *(const f32x4*)&Sp[bloc * 4];
                float r = fmaxf((sp[0] + sp[1]) + (sp[2] + sp[3]), 1e-35f);
                alpha[g] += M[g] + __logf(r);
                // scale pipeline unchanged (u unchanged at boundary)
            }

            // ---- rotate feat pipeline; build efi(t+1) with pending scale ----
            if (t + 1 < 128) {
                #pragma unroll
                for (int tile = 0; tile < 2; ++tile) {
                    f32x4 x = r1[g][tile];
                    f32x4 e;
                    e[0] = __expf(x[0]) * scp[g]; e[1] = __expf(x[1]) * scp[g];
                    e[2] = __expf(x[2]) * scp[g]; e[3] = __expf(x[3]) * scp[g];
                    efi[g][tile] = e;
                    r1[g][tile] = r2[g][tile];
                    if (t + 3 < 128)
                        r2[g][tile] = *(const f32x4*)(fb[g][tile] + (size_t)(t + 3) * 65536);
                }
                lgb[g] = lgp[g];
            }
        }
    }

    // ---- terminal accumulation (parity 0 buffers; all in-loop uses drained)
    #pragma unroll
    for (int g = 0; g < 2; ++g) {
        float s = acc[g][0][0]*te[0][0] + acc[g][0][1]*te[0][1]
                + acc[g][0][2]*te[0][2] + acc[g][0][3]*te[0][3]
                + acc[g][1][0]*te[1][0] + acc[g][1][1]*te[1][1]
                + acc[g][1][2]*te[1][2] + acc[g][1][3]*te[1][3];
        s += __shfl_xor(s, 16, 64);
        s += __shfl_xor(s, 32, 64);
        if (q == 0) Spart[0][g][bloc * 4 + w] = s;
    }
    LDS_BARRIER();
    #pragma unroll
    for (int g = 0; g < 2; ++g) {
        f32x4 sp = *(const f32x4*)&Spart[0][g][bloc * 4];
        float r = fmaxf((sp[0] + sp[1]) + (sp[2] + sp[3]), 1e-35f);
        alpha[g] += M[g] + __logf(r);
    }

    // alpha identical across waves; wave 0, q==0 lanes hold the 16+16 batches
    if (w == 0) {
        float v = (q == 0) ? (alpha[0] + alpha[1]) : 0.0f;
        #pragma unroll
        for (int off = 1; off < 64; off <<= 1)
            v += __shfl_xor(v, off, 64);
        if (lane == 0)
            atomicAdd(out, v * (1.0f / (512.0f * 16.0f)));
    }
}

extern "C" void kernel_launch(void* const* d_in, const int* in_sizes, int n_in,
                              void* d_out, int out_size, void* d_ws, size_t ws_size,
                              hipStream_t stream) {
    const float* feats = (const float*)d_in[0];   // [128,512,128] f32
    const float* trans = (const float*)d_in[1];   // [128,128] f32
    float* out = (float*)d_out;                   // scalar f32

    hipMemsetAsync(out, 0, sizeof(float), stream);
    crf_fwd<<<16, 256, 0, stream>>>(feats, trans, out);
}